// Round 1
// baseline (328.916 us; speedup 1.0000x reference)
//
#include <hip/hip_runtime.h>

#define BATCH 2
#define EDIM 192
#define NHEAD 6
#define DHEAD 32
#define HH 56
#define WW 56
#define NPIX (HH * WW)   // 3136

// ---------------- NATTEN clamped window start (matches numpy reference) ----
__device__ __forceinline__ int win_start(int i, int length, int K, int dil) {
    int NS = K >> 1;
    if (dil <= 1) {
        int s = i - NS;
        if (s < 0) s = 0;
        if (i + NS >= length) s += length - i - NS - 1;
        return s;
    }
    int ni = i - NS * dil;
    int imodd = i % dil;
    int aa = (length / dil) * dil;
    int bb = length - aa;
    int end_start = (imodd < bb) ? (length - bb + imodd - 2 * NS * dil)
                                 : (aa + imodd - K * dil);
    if (ni < 0) return imodd;
    if (i + NS * dil >= length) return end_start;
    return ni;
}

// ---------------- 1x1 conv: x(b,192,hw) * W(576,192) + b -> qkv(b,576,hw) ---
// k block (channels 192..383) pre-scaled by 32^-0.5 (after bias, as in ref).
__global__ __launch_bounds__(256) void qkv_conv_kernel(
    const float* __restrict__ x, const float* __restrict__ w,
    const float* __restrict__ bias, float* __restrict__ out)
{
    __shared__ float wl[32 * EDIM];
    const int b = blockIdx.z;
    const int o0 = blockIdx.y * 32;
    const int yx = blockIdx.x * 256 + threadIdx.x;
    for (int i = threadIdx.x; i < 32 * EDIM; i += 256)
        wl[i] = w[(size_t)(o0 + i / EDIM) * EDIM + (i % EDIM)];
    __syncthreads();
    if (yx >= NPIX) return;

    const float* xp = x + (size_t)b * EDIM * NPIX + yx;
    float acc[32];
#pragma unroll
    for (int o = 0; o < 32; ++o) acc[o] = 0.f;

    for (int c = 0; c < EDIM; c += 4) {
        const float x0 = xp[(c + 0) * NPIX];
        const float x1 = xp[(c + 1) * NPIX];
        const float x2 = xp[(c + 2) * NPIX];
        const float x3 = xp[(c + 3) * NPIX];
#pragma unroll
        for (int o = 0; o < 32; ++o) {
            const float4 wv = *reinterpret_cast<const float4*>(&wl[o * EDIM + c]);
            float a = acc[o];
            a = fmaf(x0, wv.x, a);
            a = fmaf(x1, wv.y, a);
            a = fmaf(x2, wv.z, a);
            a = fmaf(x3, wv.w, a);
            acc[o] = a;
        }
    }
    const float kscale = 0.17677669529663687f;  // 32^-0.5
    float* op = out + ((size_t)b * 3 * EDIM + o0) * NPIX + yx;
#pragma unroll
    for (int o = 0; o < 32; ++o) {
        const int oc = o0 + o;
        float r = acc[o] + bias[oc];
        if (oc >= EDIM && oc < 2 * EDIM) r *= kscale;
        op[(size_t)o * NPIX] = r;
    }
}

// ---------------- depthwise 5x5 LePE on v channels of qkv ------------------
__global__ __launch_bounds__(256) void lepe_kernel(
    const float* __restrict__ qkv, const float* __restrict__ w,
    const float* __restrict__ bias, float* __restrict__ out)
{
    const int t = blockIdx.x * 256 + threadIdx.x;
    if (t >= BATCH * EDIM * NPIX) return;
    const int yx = t % NPIX;
    const int bc = t / NPIX;
    const int c = bc % EDIM;
    const int b = bc / EDIM;
    const int y = yx / WW, x = yx % WW;

    const float* vp = qkv + ((size_t)b * 3 * EDIM + 2 * EDIM + c) * NPIX;
    const float* wp = w + (size_t)c * 25;
    float acc = bias[c];
#pragma unroll
    for (int dy = 0; dy < 5; ++dy) {
        const int yy = y + dy - 2;
        if (yy < 0 || yy >= HH) continue;
#pragma unroll
        for (int dx = 0; dx < 5; ++dx) {
            const int xx = x + dx - 2;
            if (xx < 0 || xx >= WW) continue;
            acc = fmaf(vp[yy * WW + xx], wp[dy * 5 + dx], acc);
        }
    }
    out[t] = acc;
}

// ---------------- neighborhood attention, online softmax, d-split x4 -------
// layouts: channel-major (b, n*32+d, y, x). k already scaled.
template<int K, int DIL>
__global__ __launch_bounds__(256) void na2d_kernel(
    const float* __restrict__ q, const float* __restrict__ k,
    const float* __restrict__ v, float* __restrict__ out,
    int qk_bstride, int v_bstride, int out_bstride)
{
    const int t = blockIdx.x * 256 + threadIdx.x;
    const int lane = threadIdx.x & 63;
    const int dg = lane >> 4;                       // d-group 0..3 (8 d each)
    const int pos = (t >> 6) * 16 + (lane & 15);    // 16 positions per wave
    if (pos >= BATCH * NHEAD * NPIX) return;
    const int yx = pos % NPIX;
    const int bn = pos / NPIX;
    const int b = bn / NHEAD, n = bn % NHEAD;
    const int y = yx / WW, x = yx % WW;
    const int ys = win_start(y, HH, K, DIL);
    const int xs = win_start(x, WW, K, DIL);

    const int coff = (n * DHEAD + dg * 8) * NPIX;
    const float* qp    = q + (size_t)b * qk_bstride + coff + yx;
    const float* kbase = k + (size_t)b * qk_bstride + coff;
    const float* vbase = v + (size_t)b * v_bstride  + coff;

    float qr[8];
#pragma unroll
    for (int i = 0; i < 8; ++i) qr[i] = qp[i * NPIX];

    float m = -3.0e38f, s = 0.f;
    float o[8];
#pragma unroll
    for (int i = 0; i < 8; ++i) o[i] = 0.f;

    for (int p = 0; p < K; ++p) {
        const int row = ys + p * DIL;
        const float* krow = kbase + row * WW;
        const float* vrow = vbase + row * WW;
        for (int qq = 0; qq < K; ++qq) {
            const int col = xs + qq * DIL;
            const float* kp = krow + col;
            float a0 = 0.f, a1 = 0.f;
#pragma unroll
            for (int i = 0; i < 8; i += 2) {
                a0 = fmaf(qr[i],     kp[i * NPIX],       a0);
                a1 = fmaf(qr[i + 1], kp[(i + 1) * NPIX], a1);
            }
            float dot = a0 + a1;
            dot += __shfl_xor(dot, 16);
            dot += __shfl_xor(dot, 32);   // full 32-d dot, replicated in 4 lanes
            if (dot > m) {
                const float alpha = __expf(m - dot);
                s *= alpha;
#pragma unroll
                for (int i = 0; i < 8; ++i) o[i] *= alpha;
                m = dot;
            }
            const float wgt = __expf(dot - m);
            s += wgt;
            const float* vp = vrow + col;
#pragma unroll
            for (int i = 0; i < 8; ++i) o[i] = fmaf(wgt, vp[i * NPIX], o[i]);
        }
    }
    const float inv = 1.f / s;
    float* op = out + (size_t)b * out_bstride + coff + yx;
#pragma unroll
    for (int i = 0; i < 8; ++i) op[i * NPIX] = o[i] * inv;
}

// ---------------- final 1x1 conv on (v2 + lepe) ----------------------------
__global__ __launch_bounds__(256) void out_conv_kernel(
    const float* __restrict__ v2, const float* __restrict__ lepe,
    const float* __restrict__ w, const float* __restrict__ bias,
    float* __restrict__ out)
{
    __shared__ float wl[32 * EDIM];
    const int b = blockIdx.z;
    const int o0 = blockIdx.y * 32;
    const int yx = blockIdx.x * 256 + threadIdx.x;
    for (int i = threadIdx.x; i < 32 * EDIM; i += 256)
        wl[i] = w[(size_t)(o0 + i / EDIM) * EDIM + (i % EDIM)];
    __syncthreads();
    if (yx >= NPIX) return;

    const float* vp = v2 + (size_t)b * EDIM * NPIX + yx;
    const float* lp = lepe + (size_t)b * EDIM * NPIX + yx;
    float acc[32];
#pragma unroll
    for (int o = 0; o < 32; ++o) acc[o] = 0.f;

    for (int c = 0; c < EDIM; c += 2) {
        const float r0 = vp[(c + 0) * NPIX] + lp[(c + 0) * NPIX];
        const float r1 = vp[(c + 1) * NPIX] + lp[(c + 1) * NPIX];
#pragma unroll
        for (int o = 0; o < 32; ++o) {
            const float2 wv = *reinterpret_cast<const float2*>(&wl[o * EDIM + c]);
            acc[o] = fmaf(r0, wv.x, acc[o]);
            acc[o] = fmaf(r1, wv.y, acc[o]);
        }
    }
    float* op = out + ((size_t)b * EDIM + o0) * NPIX + yx;
#pragma unroll
    for (int o = 0; o < 32; ++o)
        op[(size_t)o * NPIX] = acc[o] + bias[o0 + o];
}

extern "C" void kernel_launch(void* const* d_in, const int* in_sizes, int n_in,
                              void* d_out, int out_size, void* d_ws, size_t ws_size,
                              hipStream_t stream)
{
    const float* x      = (const float*)d_in[0];
    const float* qkv_w  = (const float*)d_in[1];
    const float* qkv_b  = (const float*)d_in[2];
    const float* lepe_w = (const float*)d_in[3];
    const float* lepe_b = (const float*)d_in[4];
    const float* out_w  = (const float*)d_in[5];
    const float* out_b  = (const float*)d_in[6];
    float* out = (float*)d_out;

    float* ws   = (float*)d_ws;
    float* qkv  = ws;                                   // 2*576*3136 floats
    float* lepe = qkv  + (size_t)BATCH * 3 * EDIM * NPIX;
    float* v1   = lepe + (size_t)BATCH * EDIM * NPIX;
    float* v2   = v1   + (size_t)BATCH * EDIM * NPIX;

    // 1) qkv projection (+ bias, k scaling)
    dim3 gq((NPIX + 255) / 256, (3 * EDIM) / 32, BATCH);
    qkv_conv_kernel<<<gq, 256, 0, stream>>>(x, qkv_w, qkv_b, qkv);

    // 2) LePE depthwise 5x5 on v channels
    const int lepe_threads = BATCH * EDIM * NPIX;
    lepe_kernel<<<(lepe_threads + 255) / 256, 256, 0, stream>>>(qkv, lepe_w, lepe_b, lepe);

    // 3) na2d pass 1: K=7, dilation 1  (q, k, v from qkv buffer)
    const int qk_bs = 3 * EDIM * NPIX;
    const int bs192 = EDIM * NPIX;
    const int attn_blocks = (BATCH * NHEAD * NPIX * 4) / 256;   // 588
    na2d_kernel<7, 1><<<attn_blocks, 256, 0, stream>>>(
        qkv, qkv + (size_t)EDIM * NPIX, qkv + (size_t)2 * EDIM * NPIX,
        v1, qk_bs, qk_bs, bs192);

    // 4) na2d pass 2: K=9, dilation 6  (v from v1)
    na2d_kernel<9, 6><<<attn_blocks, 256, 0, stream>>>(
        qkv, qkv + (size_t)EDIM * NPIX, v1,
        v2, qk_bs, bs192, bs192);

    // 5) output projection on (v2 + lepe)
    dim3 go((NPIX + 255) / 256, EDIM / 32, BATCH);
    out_conv_kernel<<<go, 256, 0, stream>>>(v2, lepe, out_w, out_b, out);
}